// Round 6
// baseline (116.660 us; speedup 1.0000x reference)
//
#include <hip/hip_runtime.h>
#include <hip/hip_bf16.h>

// SparseAttentionHead on MI355X — v6: v4's BM=32 LDS pipeline + T3/T4
// (tri-buffered FT staged 2 steps ahead, raw s_barrier, counted vmcnt(4)
// so 4 gload_lds stay in flight across each barrier).
// out[i,c] = elu( sum_j P[i,j]*F[j,c] / Z[i] ),
//   P[i,j] = exp( adj[i,j]*lrelu(a1[i]+a2[j]) ), Z[i] = sum_j P[i,j].

typedef short bf16x8 __attribute__((ext_vector_type(8)));
typedef float f32x4 __attribute__((ext_vector_type(4)));

static __device__ __forceinline__ short f2bf(float f) {
  union { float f; unsigned u; } v; v.f = f;
  unsigned r = v.u + 0x7fffu + ((v.u >> 16) & 1u);
  return (short)(r >> 16);
}

static __device__ __forceinline__ void gld16(const short* g, short* l) {
  __builtin_amdgcn_global_load_lds(
      (const __attribute__((address_space(1))) void*)g,
      (__attribute__((address_space(3))) void*)l, 16, 0, 0);
}

// K1: seq_fts = W1 @ x (fp32), store FT[c][n] = bf16, accumulate a1/a2.
__global__ __launch_bounds__(256) void k1_seqfts(
    const float* __restrict__ x, const float* __restrict__ W1,
    const float* __restrict__ wf1, const float* __restrict__ wf2,
    short* __restrict__ FT, float* __restrict__ a1, float* __restrict__ a2) {
  const int cb = blockIdx.x & 7;
  const int nb = blockIdx.x >> 3;
  const int n = nb * 256 + threadIdx.x;
  float acc[16];
#pragma unroll
  for (int i = 0; i < 16; ++i) acc[i] = 0.f;
  const float* wrow = W1 + cb * 16 * 128;
#pragma unroll 4
  for (int c = 0; c < 128; ++c) {
    float xv = x[c * 8192 + n];
#pragma unroll
    for (int cc = 0; cc < 16; ++cc) acc[cc] = fmaf(wrow[cc * 128 + c], xv, acc[cc]);
  }
  float p1 = 0.f, p2 = 0.f;
#pragma unroll
  for (int cc = 0; cc < 16; ++cc) {
    int co = cb * 16 + cc;
    FT[co * 8192 + n] = f2bf(acc[cc]);
    p1 = fmaf(wf1[co], acc[cc], p1);
    p2 = fmaf(wf2[co], acc[cc], p2);
  }
  atomicAdd(&a1[n], p1);
  atomicAdd(&a2[n], p2);
}

// K2: BM=32, BK=128, grid 256 (1 block/CU), 512 thr (8 waves).
__global__ __launch_bounds__(512, 2) void k2_attn(
    const float* __restrict__ adj, const short* __restrict__ FT,
    const float* __restrict__ a1, const float* __restrict__ a2,
    const float* __restrict__ b1p, const float* __restrict__ b2p,
    float* __restrict__ out) {
  __shared__ __align__(16) short Ftl[3][16384];  // 96 KB tri-buffer, swizzled
  __shared__ __align__(16) short Pl[2][4360];    // P dbuf, row stride 136
  __shared__ float zl[32];

  const int t = threadIdx.x;
  const int l = t & 63;
  const int w = t >> 6;
  const int r = l & 15;
  const int kg = l >> 4;
  const int i0 = blockIdx.x * 32;

  // P producer: thread t -> row t>>4, k-cols (t&15)*8 .. +8
  const int prow = t >> 4;
  const int pcg = t & 15;
  const float af = a1[i0 + prow] + b1p[0] + b2p[0];
  const float* adjp = adj + (size_t)(i0 + prow) * 8192 + pcg * 8;
  const float* a2p = a2 + pcg * 8;

  // FT staging (v4-verified): instr i covers c = i*32 + w*4 + kg; lane r = 16B
  // k-chunk; global source pre-swizzled +8*(r ^ (c&15)); LDS dest linear.
  const int swz = 8 * (r ^ ((w * 4 + kg) & 15));
  const short* fsrc0 = FT + (size_t)(0 + w * 4 + kg) * 8192 + swz;
  const short* fsrc1 = FT + (size_t)(32 + w * 4 + kg) * 8192 + swz;
  const short* fsrc2 = FT + (size_t)(64 + w * 4 + kg) * 8192 + swz;
  const short* fsrc3 = FT + (size_t)(96 + w * 4 + kg) * 8192 + swz;

  // MFMA mapping: wave w -> mtile w>>2 (16 rows), ntiles (w&3)*2 and +1.
  const int mt = w >> 2;
  const int ct0 = (w & 3) * 2;
  const int arow = mt * 16 + r;
  const int c0 = ct0 * 16 + r;

  f32x4 acc0 = {0.f, 0.f, 0.f, 0.f};
  f32x4 acc1 = {0.f, 0.f, 0.f, 0.f};
  float zacc = 0.f;

  auto STAGE = [&](int s) {                 // 4 gload_lds per wave
    const int kb = s * 128;
    short* fb = &Ftl[s % 3][w * 512];
    gld16(fsrc0 + kb, fb);
    gld16(fsrc1 + kb, fb + 4096);
    gld16(fsrc2 + kb, fb + 8192);
    gld16(fsrc3 + kb, fb + 12288);
  };

  auto build = [&](int buf, const f32x4& A0, const f32x4& A1,
                   const f32x4& Q0, const f32x4& Q1) {
    bf16x8 pv;
#pragma unroll
    for (int j = 0; j < 4; ++j) {
      float tt = af + Q0[j];
      float lr = fmaxf(tt, 0.01f * tt);
      float p = __expf(A0[j] * lr);
      zacc += p;
      pv[j] = f2bf(p);
    }
#pragma unroll
    for (int j = 0; j < 4; ++j) {
      float tt = af + Q1[j];
      float lr = fmaxf(tt, 0.01f * tt);
      float p = __expf(A1[j] * lr);
      zacc += p;
      pv[4 + j] = f2bf(p);
    }
    *(bf16x8*)&Pl[buf][prow * 136 + pcg * 8] = pv;
  };

  auto compute = [&](int pbuf, int fbuf) {
    const short* pb = &Pl[pbuf][arow * 136 + kg * 8];
    const short* fb = &Ftl[fbuf][0];
#pragma unroll
    for (int kt = 0; kt < 4; ++kt) {
      const int koff = (kg * 8 + kt * 32) ^ (r * 8);
      bf16x8 Af = *(const bf16x8*)(pb + kt * 32);
      bf16x8 B0 = *(const bf16x8*)(fb + c0 * 128 + koff);
      bf16x8 B1 = *(const bf16x8*)(fb + (c0 + 16) * 128 + koff);
      acc0 = __builtin_amdgcn_mfma_f32_16x16x32_bf16(Af, B0, acc0, 0, 0, 0);
      acc1 = __builtin_amdgcn_mfma_f32_16x16x32_bf16(Af, B1, acc1, 0, 0, 0);
    }
  };

  // body(s): prefetch adj(s+2) -> refill set; STAGE(s+2); build P(s+1) from
  // consume set; MFMA(s); lgkm0; vmcnt(4) [leaves STAGE(s+2) in flight]; barrier.
  auto body = [&](int s, const f32x4& uA0, const f32x4& uA1,
                  const f32x4& uQ0, const f32x4& uQ1,
                  f32x4& fA0, f32x4& fA1, f32x4& fQ0, f32x4& fQ1) {
    __builtin_amdgcn_sched_barrier(0);
    if (s + 2 < 64) {                       // adj/a2(s+2) -> refill regs
      const int kb2 = (s + 2) * 128;
      fA0 = *(const f32x4*)(adjp + kb2);
      fA1 = *(const f32x4*)(adjp + kb2 + 4);
      fQ0 = *(const f32x4*)(a2p + kb2);
      fQ1 = *(const f32x4*)(a2p + kb2 + 4);
    }
    __builtin_amdgcn_sched_barrier(0);      // adj loads stay OLDER than STAGE
    if (s + 2 < 64) STAGE(s + 2);
    __builtin_amdgcn_sched_barrier(0);
    if (s + 1 < 64) build((s + 1) & 1, uA0, uA1, uQ0, uQ1);
    compute(s & 1, s % 3);
    asm volatile("s_waitcnt lgkmcnt(0)" ::: "memory");
    if (s < 62) {
      asm volatile("s_waitcnt vmcnt(4)" ::: "memory");   // STAGE(s+1) done
    } else {
      asm volatile("s_waitcnt vmcnt(0)" ::: "memory");   // tail: drain
    }
    __builtin_amdgcn_s_barrier();
  };

  // ---- prologue: STAGE(0),STAGE(1); adj(0)->t, adj(1)->O; build P(0) ----
  STAGE(0);
  STAGE(1);
  __builtin_amdgcn_sched_barrier(0);        // keep adj loads younger than gloads
  f32x4 tA0 = *(const f32x4*)(adjp);
  f32x4 tA1 = *(const f32x4*)(adjp + 4);
  f32x4 tQ0 = *(const f32x4*)(a2p);
  f32x4 tQ1 = *(const f32x4*)(a2p + 4);
  f32x4 oA0 = *(const f32x4*)(adjp + 128);
  f32x4 oA1 = *(const f32x4*)(adjp + 132);
  f32x4 oQ0 = *(const f32x4*)(a2p + 128);
  f32x4 oQ1 = *(const f32x4*)(a2p + 132);
  __builtin_amdgcn_sched_barrier(0);
  build(0, tA0, tA1, tQ0, tQ1);             // compiler's wait on tA covers S0,S1
  f32x4 eA0 = {0, 0, 0, 0}, eA1 = {0, 0, 0, 0}, eQ0 = {0, 0, 0, 0}, eQ1 = {0, 0, 0, 0};
  asm volatile("s_waitcnt lgkmcnt(0)" ::: "memory");
  __builtin_amdgcn_s_barrier();             // P(0)+Ftl[0] visible to all

  for (int s = 0; s < 64; s += 2) {
    body(s, oA0, oA1, oQ0, oQ1, eA0, eA1, eQ0, eQ1);      // consume adj(s+1)=O
    body(s + 1, eA0, eA1, eQ0, eQ1, oA0, oA1, oQ0, oQ1);  // consume adj(s+2)=E
  }
  __builtin_amdgcn_sched_barrier(0);

  // ---- Z: 16 threads per row ----
  float zr = zacc;
  zr += __shfl_down(zr, 8, 16);
  zr += __shfl_down(zr, 4, 16);
  zr += __shfl_down(zr, 2, 16);
  zr += __shfl_down(zr, 1, 16);
  if (pcg == 0) zl[prow] = zr;
  __syncthreads();

  // ---- epilogue: C/D layout col=l&15, row=4*kg+q ----
#pragma unroll
  for (int q = 0; q < 4; ++q) {
    const int row = mt * 16 + kg * 4 + q;
    const float inv = 1.0f / zl[row];
    float v0 = acc0[q] * inv;
    v0 = v0 > 0.f ? v0 : __expf(v0) - 1.f;
    out[(size_t)(i0 + row) * 128 + c0] = v0;
    float v1 = acc1[q] * inv;
    v1 = v1 > 0.f ? v1 : __expf(v1) - 1.f;
    out[(size_t)(i0 + row) * 128 + c0 + 16] = v1;
  }
}

extern "C" void kernel_launch(void* const* d_in, const int* in_sizes, int n_in,
                              void* d_out, int out_size, void* d_ws, size_t ws_size,
                              hipStream_t stream) {
  const float* x   = (const float*)d_in[0];
  // d_in[1] = edge_index (unused by the reference computation)
  const float* adj = (const float*)d_in[2];
  const float* W1  = (const float*)d_in[3];
  const float* wf1 = (const float*)d_in[4];
  const float* b1  = (const float*)d_in[5];
  const float* wf2 = (const float*)d_in[6];
  const float* b2  = (const float*)d_in[7];
  float* out = (float*)d_out;

  short* FT = (short*)d_ws;                                    // 128*8192 bf16 = 2MB
  float* a1 = (float*)((char*)d_ws + (size_t)2 * 1024 * 1024); // 8192 f32
  float* a2 = a1 + 8192;                                       // 8192 f32

  hipMemsetAsync(a1, 0, 2 * 8192 * sizeof(float), stream);
  k1_seqfts<<<256, 256, 0, stream>>>(x, W1, wf1, wf2, FT, a1, a2);
  k2_attn<<<256, 512, 0, stream>>>(adj, FT, a1, a2, b1, b2, out);
}